// Round 4
// baseline (139.070 us; speedup 1.0000x reference)
//
#include <hip/hip_runtime.h>
#include <math.h>

// Problem constants
constexpr int B_  = 4;
constexpr int C_  = 256;
constexpr int HW_ = 4096;   // 64*64
constexpr int CR_ = 16;     // c / RED
constexpr int CQ_ = 32;     // c / 8
constexpr int NB_ = 256;    // persistent grid = 1 block/CU (co-residency guaranteed)

__device__ __forceinline__ float sigmoidf_(float x){ return 1.f/(1.f+expf(-x)); }

// Device-scope barrier: monotonic counter, release/acquire + agent fences (G16).
__device__ __forceinline__ void gbar(int* cnt, int gen){
  __syncthreads();
  if (threadIdx.x == 0){
    __threadfence();   // publish this block's prior global writes
    __hip_atomic_fetch_add(cnt, 1, __ATOMIC_RELEASE, __HIP_MEMORY_SCOPE_AGENT);
    while (__hip_atomic_load(cnt, __ATOMIC_ACQUIRE, __HIP_MEMORY_SCOPE_AGENT) < gen*NB_)
      __builtin_amdgcn_s_sleep(1);
    __threadfence();   // invalidate stale caches before consuming others' writes
  }
  __syncthreads();
}

__global__ void __launch_bounds__(256, 1) kFused(
    const float* __restrict__ x,
    const float* __restrict__ w1,  const float* __restrict__ w2,
    const float* __restrict__ wsp,
    const float* __restrict__ wq,  const float* __restrict__ bq,
    const float* __restrict__ wk,  const float* __restrict__ bk,
    const float* __restrict__ wv,  const float* __restrict__ bv,
    const float* __restrict__ gm,
    int* cnt, float* avg, float* mxv, float* avgs, float* maxs,
    float* qb, float* kb, float* vb, float* out){

  __shared__ union {
    struct {
      float sa[C_], sm[C_], pa[C_], pm[C_], hs[CR_], satt[C_];
      float4 rs[16][16], rm[16][16];
      float savg[10][64], smax[10][64], ssig[4][64], swsp[98];
    } p;                          // phases 1-3 (~20 KB)
    float sx[C_*32];              // phase 4 (32 KB)
    struct { float sq[CQ_], red[8], sl[HW_]; } f;  // phase 5 (~16.5 KB)
  } S;

  int t = threadIdx.x, bx = blockIdx.x;
  int w = t >> 6, lane = t & 63;

  // ---- Phase 1: per-(b,c) mean & max. One wave per channel, 4 channels/block ----
  {
    int bc = bx*4 + w;
    const float4* r4 = (const float4*)(x + (size_t)bc*HW_);
    float s = 0.f, m = -INFINITY;
    #pragma unroll
    for (int k2 = 0; k2 < 16; k2++){
      float4 v = r4[lane + k2*64];
      s += v.x+v.y+v.z+v.w;
      m = fmaxf(m, fmaxf(fmaxf(v.x,v.y), fmaxf(v.z,v.w)));
    }
    for (int off = 32; off; off >>= 1){
      s += __shfl_down(s, off);
      m = fmaxf(m, __shfl_down(m, off));
    }
    if (!lane){ avg[bc] = s*(1.f/HW_); mxv[bc] = m; }
  }
  gbar(cnt, 1);

  // ---- Phase 2: channel-attention MLP (in LDS), then per-row spatial stats ----
  int b = bx >> 6;
  {
    if (t < 98) S.p.swsp[t] = wsp[t];
    S.p.sa[t] = avg[b*C_+t]; S.p.sm[t] = mxv[b*C_+t];
    __syncthreads();
    int h = t >> 4, seg = t & 15;               // 16 hidden x 16 channel-segments
    float qa = 0.f, qm = 0.f;
    #pragma unroll
    for (int c2 = 0; c2 < 16; c2++){
      int c = seg*16 + c2;
      float ww = w1[h*C_ + c];
      qa += ww*S.p.sa[c]; qm += ww*S.p.sm[c];
    }
    S.p.pa[t] = qa; S.p.pm[t] = qm;
    __syncthreads();
    if (t < CR_){
      float ha = 0.f, hm = 0.f;
      #pragma unroll
      for (int s2 = 0; s2 < 16; s2++){ ha += S.p.pa[t*16+s2]; hm += S.p.pm[t*16+s2]; }
      S.p.hs[t] = fmaxf(ha, 0.f) + fmaxf(hm, 0.f);
    }
    __syncthreads();
    float o = 0.f;
    #pragma unroll
    for (int h2 = 0; h2 < CR_; h2++) o += S.p.hs[h2]*w2[t*CR_+h2];  // w2 is [C, CR]
    S.p.satt[t] = sigmoidf_(o);
    __syncthreads();

    // per-row channel mean/max of x*att; block = (b, row r)
    int r = bx & 63;
    int cg = t >> 4, q = t & 15;
    const float4* x4 = (const float4*)x;
    float4 s = {0.f,0.f,0.f,0.f};
    float4 m = {-INFINITY,-INFINITY,-INFINITY,-INFINITY};
    #pragma unroll
    for (int j = 0; j < 16; j++){
      int c = cg*16 + j;
      float a = S.p.satt[c];
      float4 v = x4[(size_t)(b*C_+c)*(HW_/4) + (r<<4) + q];
      float vx=v.x*a, vy=v.y*a, vz=v.z*a, vw=v.w*a;
      s.x+=vx; s.y+=vy; s.z+=vz; s.w+=vw;
      m.x=fmaxf(m.x,vx); m.y=fmaxf(m.y,vy); m.z=fmaxf(m.z,vz); m.w=fmaxf(m.w,vw);
    }
    S.p.rs[cg][q] = s; S.p.rm[cg][q] = m;
    __syncthreads();
    if (t < 16){
      float4 Sv = {0.f,0.f,0.f,0.f};
      float4 Mv = {-INFINITY,-INFINITY,-INFINITY,-INFINITY};
      #pragma unroll
      for (int g2 = 0; g2 < 16; g2++){
        float4 a = S.p.rs[g2][t], b2 = S.p.rm[g2][t];
        Sv.x+=a.x; Sv.y+=a.y; Sv.z+=a.z; Sv.w+=a.w;
        Mv.x=fmaxf(Mv.x,b2.x); Mv.y=fmaxf(Mv.y,b2.y); Mv.z=fmaxf(Mv.z,b2.z); Mv.w=fmaxf(Mv.w,b2.w);
      }
      Sv.x*=(1.f/C_); Sv.y*=(1.f/C_); Sv.z*=(1.f/C_); Sv.w*=(1.f/C_);
      ((float4*)(avgs + b*HW_ + r*64))[t] = Sv;
      ((float4*)(maxs + b*HW_ + r*64))[t] = Mv;
    }
  }
  gbar(cnt, 2);

  // ---- Phase 3: halo stage + 7x7 conv + sigmoid + out = x*att*sig ----
  {
    int rem = bx & 63, rt = rem >> 2, cp = rem & 3;
    for (int idx = t; idx < 640; idx += 256){
      int row = idx >> 6, col = idx & 63;
      int gr = rt*4 - 3 + row;                  // global image row (zero-padded)
      float s = 0.f, m = 0.f;
      if ((unsigned)gr < 64u){
        s = avgs[b*HW_ + gr*64 + col];
        m = maxs[b*HW_ + gr*64 + col];
      }
      S.p.savg[row][col] = s; S.p.smax[row][col] = m;
    }
    __syncthreads();
    int trow = t >> 6, col = t & 63;
    float acc = 0.f;
    #pragma unroll
    for (int ky = 0; ky < 7; ky++){
      #pragma unroll
      for (int kx = 0; kx < 7; kx++){
        int gx = col - 3 + kx;
        if ((unsigned)gx < 64u)
          acc += S.p.savg[trow+ky][gx]*S.p.swsp[ky*7+kx]
               + S.p.smax[trow+ky][gx]*S.p.swsp[49+ky*7+kx];
      }
    }
    S.p.ssig[trow][col] = sigmoidf_(acc);
    __syncthreads();
    int f4id = t & 63;
    float4 sg4 = ((const float4*)S.p.ssig)[f4id];
    int imgo = rt*64 + f4id;                    // float4 index within image
    const float4* x4 = (const float4*)x;
    float4* o4 = (float4*)out;
    #pragma unroll
    for (int jj = 0; jj < 16; jj++){
      int lc = (t>>6) + jj*4;                   // local channel (wave-uniform)
      float a = S.p.satt[cp*64 + lc];
      size_t g = (size_t)(b*C_ + cp*64 + lc)*(HW_/4) + imgo;
      float4 v = x4[g];
      float4 rr;
      rr.x = v.x*a*sg4.x; rr.y = v.y*a*sg4.y; rr.z = v.z*a*sg4.z; rr.w = v.w*a*sg4.w;
      o4[g] = rr;
    }
  }

  // ---- Gated non-local attention (uniform branch; gamma==0 -> done) ----
  float g = gm[0];
  if (g == 0.f) return;

  gbar(cnt, 3);   // out fully written, visible to all blocks

  // Phase 4: q,k,v 1x1 convs of out. Grid-stride over 512 tiles of 32 px.
  for (int bx2 = bx; bx2 < 512; bx2 += NB_){
    int b2 = bx2 >> 7, tile = bx2 & 127, p0 = tile*32;
    for (int idx = t; idx < C_*32; idx += 256){
      int c = idx >> 5, px = idx & 31;
      S.sx[idx] = out[(size_t)(b2*C_+c)*HW_ + p0 + px];
    }
    __syncthreads();
    for (int oi = t; oi < CQ_*32; oi += 256){
      int o = oi >> 5, px = oi & 31;
      float aq = bq[o], ak = bk[o];
      for (int c = 0; c < C_; c++){ float xv = S.sx[c*32+px]; aq += xv*wq[o*C_+c]; ak += xv*wk[o*C_+c]; }
      qb[(size_t)(b2*CQ_+o)*HW_ + p0 + px] = aq;
      kb[(size_t)(b2*CQ_+o)*HW_ + p0 + px] = ak;
    }
    for (int oi = t; oi < C_*32; oi += 256){
      int o = oi >> 5, px = oi & 31;
      float av = bv[o];
      for (int c = 0; c < C_; c++) av += S.sx[c*32+px]*wv[o*C_+c];
      vb[(size_t)(b2*C_+o)*HW_ + p0 + px] = av;
    }
    __syncthreads();
  }
  gbar(cnt, 4);

  // Phase 5: softmax(q_i . k); out[b,c,i] += gamma * sum_j p_j v[c,j]
  for (int gi = bx; gi < B_*HW_; gi += NB_){
    int b2 = gi >> 12, i = gi & (HW_-1);
    if (t < CQ_) S.f.sq[t] = qb[(size_t)(b2*CQ_+t)*HW_ + i];
    __syncthreads();
    float lmax = -INFINITY;
    for (int j = t; j < HW_; j += 256){
      float l = 0.f;
      for (int d = 0; d < CQ_; d++) l += S.f.sq[d]*kb[(size_t)(b2*CQ_+d)*HW_ + j];
      S.f.sl[j] = l; lmax = fmaxf(lmax, l);
    }
    for (int off = 32; off; off >>= 1) lmax = fmaxf(lmax, __shfl_down(lmax, off));
    if (!(t & 63)) S.f.red[t>>6] = lmax;
    __syncthreads();
    float M = fmaxf(fmaxf(S.f.red[0],S.f.red[1]), fmaxf(S.f.red[2],S.f.red[3]));
    float lsum = 0.f;
    for (int j = t; j < HW_; j += 256){ float p = expf(S.f.sl[j]-M); S.f.sl[j] = p; lsum += p; }
    for (int off = 32; off; off >>= 1) lsum += __shfl_down(lsum, off);
    if (!(t & 63)) S.f.red[4+(t>>6)] = lsum;
    __syncthreads();
    float inv = g/(S.f.red[4]+S.f.red[5]+S.f.red[6]+S.f.red[7]);
    float acc = 0.f;
    const float* vrow = vb + (size_t)(b2*C_+t)*HW_;
    for (int j = 0; j < HW_; j++) acc += S.f.sl[j]*vrow[j];
    out[(size_t)(b2*C_+t)*HW_ + i] += acc*inv;
    __syncthreads();
  }
}

extern "C" void kernel_launch(void* const* d_in, const int* in_sizes, int n_in,
                              void* d_out, int out_size, void* d_ws, size_t ws_size,
                              hipStream_t stream){
  const float* x   = (const float*)d_in[0];
  const float* w1  = (const float*)d_in[1];
  const float* w2  = (const float*)d_in[2];
  const float* wsp = (const float*)d_in[3];
  const float* wq  = (const float*)d_in[4];
  const float* bq  = (const float*)d_in[5];
  const float* wk  = (const float*)d_in[6];
  const float* bk  = (const float*)d_in[7];
  const float* wv  = (const float*)d_in[8];
  const float* bv  = (const float*)d_in[9];
  const float* gm  = (const float*)d_in[10];
  float* out = (float*)d_out;
  float* ws  = (float*)d_ws;

  int*   cnt  = (int*)ws;                 // 64 B barrier region
  float* avg  = ws + 16;                  // 1024
  float* mxv  = avg  + B_*C_;             // 1024
  float* avgs = mxv  + B_*C_;             // B*HW = 16384
  float* maxs = avgs + B_*HW_;            // 16384
  float* qb   = maxs + B_*HW_;            // B*CQ*HW = 524288 (gated)
  float* kb   = qb   + B_*CQ_*HW_;        // 524288 (gated)
  float* vb   = kb   + B_*CQ_*HW_;        // B*C*HW = 4194304 (gated)
  (void)in_sizes; (void)n_in; (void)out_size; (void)ws_size;

  hipMemsetAsync(cnt, 0, 64, stream);     // zero barrier counter (graph-capturable)
  kFused<<<NB_, 256, 0, stream>>>(x, w1, w2, wsp, wq, bq, wk, bk, wv, bv, gm,
                                  cnt, avg, mxv, avgs, maxs, qb, kb, vb, out);
}

// Round 5
// 105.177 us; speedup vs baseline: 1.3222x; 1.3222x over previous
//
#include <hip/hip_runtime.h>
#include <math.h>

// Problem constants
constexpr int B_  = 4;
constexpr int C_  = 256;
constexpr int HW_ = 4096;   // 64*64
constexpr int CR_ = 16;     // c / RED
constexpr int CQ_ = 32;     // c / 8
constexpr int NAB = 256;    // attention grid (1 block/CU, co-resident)

__device__ __forceinline__ float sigmoidf_(float x){ return 1.f/(1.f+expf(-x)); }

// ---- A: per (b,c) mean & max over hw. grid = B*C = 1024 blocks, 256 thr ----
__global__ void kA(const float* __restrict__ x, float* __restrict__ avg, float* __restrict__ mxv){
  int bc = blockIdx.x;
  const float4* r4 = (const float4*)(x + (size_t)bc*HW_);
  float s = 0.f, m = -INFINITY;
  #pragma unroll
  for (int i = 0; i < 4; i++){
    float4 v = r4[threadIdx.x + i*256];
    s += v.x+v.y+v.z+v.w;
    m = fmaxf(m, fmaxf(fmaxf(v.x,v.y), fmaxf(v.z,v.w)));
  }
  for (int off = 32; off; off >>= 1){
    s += __shfl_down(s, off);
    m = fmaxf(m, __shfl_down(m, off));
  }
  __shared__ float ss[4], sm[4];
  int w = threadIdx.x >> 6, lane = threadIdx.x & 63;
  if (!lane){ ss[w] = s; sm[w] = m; }
  __syncthreads();
  if (!threadIdx.x){
    avg[bc] = (ss[0]+ss[1]+ss[2]+ss[3]) * (1.f/HW_);
    mxv[bc] = fmaxf(fmaxf(sm[0],sm[1]), fmaxf(sm[2],sm[3]));
  }
}

// ---- BC: channel-MLP -> satt (stored to attg), then per-row spatial stats.
//      grid = B*64 rows = 256 blocks, 256 thr. Block = (b, image row r). ----
__global__ void kBC(const float* __restrict__ x,
                    const float* __restrict__ avg, const float* __restrict__ mxv,
                    const float* __restrict__ w1,  const float* __restrict__ w2,
                    float* __restrict__ attg,
                    float* __restrict__ avgs, float* __restrict__ maxs){
  int b = blockIdx.x >> 6, r = blockIdx.x & 63, t = threadIdx.x;
  __shared__ float sa[C_], sm[C_], pa[C_], pm[C_], hs[CR_], satt[C_];
  __shared__ float4 rs[16][16], rm[16][16];
  sa[t] = avg[b*C_+t]; sm[t] = mxv[b*C_+t];
  __syncthreads();
  int h = t >> 4, seg = t & 15;                 // 16 hidden x 16 channel-segments
  float qa = 0.f, qm = 0.f;
  #pragma unroll
  for (int c2 = 0; c2 < 16; c2++){
    int c = seg*16 + c2;
    float ww = w1[h*C_ + c];
    qa += ww*sa[c]; qm += ww*sm[c];
  }
  pa[t] = qa; pm[t] = qm;
  __syncthreads();
  if (t < CR_){
    float ha = 0.f, hm = 0.f;
    #pragma unroll
    for (int s2 = 0; s2 < 16; s2++){ ha += pa[t*16+s2]; hm += pm[t*16+s2]; }
    hs[t] = fmaxf(ha, 0.f) + fmaxf(hm, 0.f);    // relu(h_avg)+relu(h_max), shared w2
  }
  __syncthreads();
  float o = 0.f;
  #pragma unroll
  for (int h2 = 0; h2 < CR_; h2++) o += hs[h2]*w2[t*CR_+h2];   // w2 is [C, CR]
  float attv = sigmoidf_(o);
  satt[t] = attv;
  if (r == 0) attg[b*C_+t] = attv;              // one writer per (b,c)
  __syncthreads();

  // per-row channel mean/max of x*att
  int cg = t >> 4, q = t & 15;
  const float4* x4 = (const float4*)x;
  float4 s = {0.f,0.f,0.f,0.f};
  float4 m = {-INFINITY,-INFINITY,-INFINITY,-INFINITY};
  #pragma unroll
  for (int j = 0; j < 16; j++){
    int c = cg*16 + j;
    float a = satt[c];
    float4 v = x4[(size_t)(b*C_+c)*(HW_/4) + (r<<4) + q];
    float vx=v.x*a, vy=v.y*a, vz=v.z*a, vw=v.w*a;
    s.x+=vx; s.y+=vy; s.z+=vz; s.w+=vw;
    m.x=fmaxf(m.x,vx); m.y=fmaxf(m.y,vy); m.z=fmaxf(m.z,vz); m.w=fmaxf(m.w,vw);
  }
  rs[cg][q] = s; rm[cg][q] = m;
  __syncthreads();
  if (t < 16){
    float4 Sv = {0.f,0.f,0.f,0.f};
    float4 Mv = {-INFINITY,-INFINITY,-INFINITY,-INFINITY};
    #pragma unroll
    for (int g2 = 0; g2 < 16; g2++){
      float4 a = rs[g2][t], b2 = rm[g2][t];
      Sv.x+=a.x; Sv.y+=a.y; Sv.z+=a.z; Sv.w+=a.w;
      Mv.x=fmaxf(Mv.x,b2.x); Mv.y=fmaxf(Mv.y,b2.y); Mv.z=fmaxf(Mv.z,b2.z); Mv.w=fmaxf(Mv.w,b2.w);
    }
    Sv.x*=(1.f/C_); Sv.y*=(1.f/C_); Sv.z*=(1.f/C_); Sv.w*=(1.f/C_);
    ((float4*)(avgs + b*HW_ + r*64))[t] = Sv;
    ((float4*)(maxs + b*HW_ + r*64))[t] = Mv;
  }
}

// ---- D: halo stage + 7x7 conv + sigmoid + out = x*att*sig (float4).
//      grid = B*16rowtiles*8cparts = 512 blocks (2/CU), 32 channels/block ----
__global__ void kD2s(const float* __restrict__ x, const float* __restrict__ attg,
                     const float* __restrict__ avgs, const float* __restrict__ maxs,
                     const float* __restrict__ wsp, float* __restrict__ out,
                     int* __restrict__ cnt){
  int bx = blockIdx.x;
  int b = bx >> 7, rem = bx & 127, rt = rem >> 3, cp = rem & 7;
  int t = threadIdx.x;
  if (bx == 0 && t == 0) cnt[0] = 0;            // reset kAttn barrier (stream order)
  __shared__ float savg[10][64], smax[10][64], ssig[4][64], satt[32], swsp[98];
  if (t < 98) swsp[t] = wsp[t];
  if (t < 32) satt[t] = attg[b*C_ + cp*32 + t];
  for (int idx = t; idx < 640; idx += 256){
    int row = idx >> 6, col = idx & 63;
    int gr = rt*4 - 3 + row;                    // global image row (zero-padded)
    float s = 0.f, m = 0.f;
    if ((unsigned)gr < 64u){
      s = avgs[b*HW_ + gr*64 + col];
      m = maxs[b*HW_ + gr*64 + col];
    }
    savg[row][col] = s; smax[row][col] = m;
  }
  __syncthreads();
  int trow = t >> 6, col = t & 63;
  float acc = 0.f;
  #pragma unroll
  for (int ky = 0; ky < 7; ky++){
    #pragma unroll
    for (int kx = 0; kx < 7; kx++){
      int gx = col - 3 + kx;
      if ((unsigned)gx < 64u)
        acc += savg[trow+ky][gx]*swsp[ky*7+kx] + smax[trow+ky][gx]*swsp[49+ky*7+kx];
    }
  }
  ssig[trow][col] = sigmoidf_(acc);
  __syncthreads();
  int f4id = t & 63;
  float4 sg4 = ((const float4*)ssig)[f4id];
  int imgo = rt*64 + f4id;                      // float4 index within image
  const float4* x4 = (const float4*)x;
  float4* o4 = (float4*)out;
  #pragma unroll
  for (int jj = 0; jj < 8; jj++){
    int lc = (t>>6) + jj*4;                     // local channel 0..31 (wave-uniform)
    float a = satt[lc];
    size_t g = (size_t)(b*C_ + cp*32 + lc)*(HW_/4) + imgo;
    float4 v = x4[g];
    float4 rr;
    rr.x = v.x*a*sg4.x; rr.y = v.y*a*sg4.y; rr.z = v.z*a*sg4.z; rr.w = v.w*a*sg4.w;
    o4[g] = rr;
  }
}

// ---- Gated non-local attention, single kernel (runs only when gamma != 0).
//      Internal device barrier between qkv and softmax phases; 256 blocks
//      (1/CU, co-resident). Barrier cost never paid when gamma==0. ----
__global__ void kAttn(const float* __restrict__ gamma, float* __restrict__ out,
                      const float* __restrict__ wq, const float* __restrict__ bq,
                      const float* __restrict__ wk, const float* __restrict__ bk,
                      const float* __restrict__ wv, const float* __restrict__ bv,
                      float* __restrict__ qb, float* __restrict__ kb,
                      float* __restrict__ vb, int* __restrict__ cnt){
  float g = gamma[0];
  if (g == 0.f) return;
  int t = threadIdx.x, bx = blockIdx.x;
  __shared__ union {
    float sx[C_*32];                                  // qkv phase (32 KB)
    struct { float sq[CQ_], red[8], sl[HW_]; } f;     // softmax phase
  } S;

  for (int bx2 = bx; bx2 < 512; bx2 += NAB){
    int b2 = bx2 >> 7, tile = bx2 & 127, p0 = tile*32;
    for (int idx = t; idx < C_*32; idx += 256){
      int c = idx >> 5, px = idx & 31;
      S.sx[idx] = out[(size_t)(b2*C_+c)*HW_ + p0 + px];
    }
    __syncthreads();
    for (int oi = t; oi < CQ_*32; oi += 256){
      int o = oi >> 5, px = oi & 31;
      float aq = bq[o], ak = bk[o];
      for (int c = 0; c < C_; c++){ float xv = S.sx[c*32+px]; aq += xv*wq[o*C_+c]; ak += xv*wk[o*C_+c]; }
      qb[(size_t)(b2*CQ_+o)*HW_ + p0 + px] = aq;
      kb[(size_t)(b2*CQ_+o)*HW_ + p0 + px] = ak;
    }
    for (int oi = t; oi < C_*32; oi += 256){
      int o = oi >> 5, px = oi & 31;
      float av = bv[o];
      for (int c = 0; c < C_; c++) av += S.sx[c*32+px]*wv[o*C_+c];
      vb[(size_t)(b2*C_+o)*HW_ + p0 + px] = av;
    }
    __syncthreads();
  }

  // device-scope barrier (only in gamma!=0 path)
  __syncthreads();
  if (t == 0){
    __threadfence();
    __hip_atomic_fetch_add(cnt, 1, __ATOMIC_RELEASE, __HIP_MEMORY_SCOPE_AGENT);
    while (__hip_atomic_load(cnt, __ATOMIC_ACQUIRE, __HIP_MEMORY_SCOPE_AGENT) < NAB)
      __builtin_amdgcn_s_sleep(1);
    __threadfence();
  }
  __syncthreads();

  for (int gi = bx; gi < B_*HW_; gi += NAB){
    int b2 = gi >> 12, i = gi & (HW_-1);
    if (t < CQ_) S.f.sq[t] = qb[(size_t)(b2*CQ_+t)*HW_ + i];
    __syncthreads();
    float lmax = -INFINITY;
    for (int j = t; j < HW_; j += 256){
      float l = 0.f;
      for (int d = 0; d < CQ_; d++) l += S.f.sq[d]*kb[(size_t)(b2*CQ_+d)*HW_ + j];
      S.f.sl[j] = l; lmax = fmaxf(lmax, l);
    }
    for (int off = 32; off; off >>= 1) lmax = fmaxf(lmax, __shfl_down(lmax, off));
    if (!(t & 63)) S.f.red[t>>6] = lmax;
    __syncthreads();
    float M = fmaxf(fmaxf(S.f.red[0],S.f.red[1]), fmaxf(S.f.red[2],S.f.red[3]));
    float lsum = 0.f;
    for (int j = t; j < HW_; j += 256){ float p = expf(S.f.sl[j]-M); S.f.sl[j] = p; lsum += p; }
    for (int off = 32; off; off >>= 1) lsum += __shfl_down(lsum, off);
    if (!(t & 63)) S.f.red[4+(t>>6)] = lsum;
    __syncthreads();
    float inv = g/(S.f.red[4]+S.f.red[5]+S.f.red[6]+S.f.red[7]);
    float acc = 0.f;
    const float* vrow = vb + (size_t)(b2*C_+t)*HW_;
    for (int j = 0; j < HW_; j++) acc += S.f.sl[j]*vrow[j];
    out[(size_t)(b2*C_+t)*HW_ + i] += acc*inv;
    __syncthreads();
  }
}

extern "C" void kernel_launch(void* const* d_in, const int* in_sizes, int n_in,
                              void* d_out, int out_size, void* d_ws, size_t ws_size,
                              hipStream_t stream){
  const float* x   = (const float*)d_in[0];
  const float* w1  = (const float*)d_in[1];
  const float* w2  = (const float*)d_in[2];
  const float* wsp = (const float*)d_in[3];
  const float* wq  = (const float*)d_in[4];
  const float* bq  = (const float*)d_in[5];
  const float* wk  = (const float*)d_in[6];
  const float* bk  = (const float*)d_in[7];
  const float* wv  = (const float*)d_in[8];
  const float* bv  = (const float*)d_in[9];
  const float* gm  = (const float*)d_in[10];
  float* out = (float*)d_out;
  float* ws  = (float*)d_ws;

  int*   cnt  = (int*)ws;                 // 64 B barrier region
  float* avg  = ws + 16;                  // 1024
  float* mxv  = avg  + B_*C_;             // 1024
  float* attg = mxv  + B_*C_;             // 1024
  float* avgs = attg + B_*C_;             // B*HW = 16384
  float* maxs = avgs + B_*HW_;            // 16384
  float* qb   = maxs + B_*HW_;            // B*CQ*HW = 524288 (gated)
  float* kb   = qb   + B_*CQ_*HW_;        // 524288 (gated)
  float* vb   = kb   + B_*CQ_*HW_;        // B*C*HW = 4194304 (gated)
  size_t need_attn = (size_t)((vb + (size_t)B_*C_*HW_) - ws) * sizeof(float);
  (void)in_sizes; (void)n_in; (void)out_size;

  kA  <<<B_*C_, 256, 0, stream>>>(x, avg, mxv);
  kBC <<<256,   256, 0, stream>>>(x, avg, mxv, w1, w2, attg, avgs, maxs);
  kD2s<<<512,   256, 0, stream>>>(x, attg, avgs, maxs, wsp, out, cnt);

  // Non-local attention: correct for any gamma; empty launch when gamma==0.
  if (ws_size >= need_attn)
    kAttn<<<NAB, 256, 0, stream>>>(gm, out, wq, bq, wk, bk, wv, bv, qb, kb, vb, cnt);
}

// Round 6
// 102.919 us; speedup vs baseline: 1.3513x; 1.0219x over previous
//
#include <hip/hip_runtime.h>
#include <math.h>

// Problem constants
constexpr int B_  = 4;
constexpr int C_  = 256;
constexpr int HW_ = 4096;   // 64*64
constexpr int CR_ = 16;     // c / RED
constexpr int CQ_ = 32;     // c / 8
constexpr int NDB = 512;    // kD3 grid (2 blocks/CU, co-resident via launch_bounds)

__device__ __forceinline__ float sigmoidf_(float x){ return 1.f/(1.f+expf(-x)); }

// ---- A: per (b,c) mean & max over hw. grid = B*C = 1024 blocks, 256 thr ----
__global__ void kA(const float* __restrict__ x, float* __restrict__ avg, float* __restrict__ mxv){
  int bc = blockIdx.x;
  const float4* r4 = (const float4*)(x + (size_t)bc*HW_);
  float s = 0.f, m = -INFINITY;
  #pragma unroll
  for (int i = 0; i < 4; i++){
    float4 v = r4[threadIdx.x + i*256];
    s += v.x+v.y+v.z+v.w;
    m = fmaxf(m, fmaxf(fmaxf(v.x,v.y), fmaxf(v.z,v.w)));
  }
  for (int off = 32; off; off >>= 1){
    s += __shfl_down(s, off);
    m = fmaxf(m, __shfl_down(m, off));
  }
  __shared__ float ss[4], sm[4];
  int w = threadIdx.x >> 6, lane = threadIdx.x & 63;
  if (!lane){ ss[w] = s; sm[w] = m; }
  __syncthreads();
  if (!threadIdx.x){
    avg[bc] = (ss[0]+ss[1]+ss[2]+ss[3]) * (1.f/HW_);
    mxv[bc] = fmaxf(fmaxf(sm[0],sm[1]), fmaxf(sm[2],sm[3]));
  }
}

// ---- BC: channel-MLP -> satt (stored to attg), then per-row spatial stats.
//      grid = B*64 rows = 256 blocks. x loads issued EARLY (overlap w/ MLP). ----
__global__ void kBC(const float* __restrict__ x,
                    const float* __restrict__ avg, const float* __restrict__ mxv,
                    const float* __restrict__ w1,  const float* __restrict__ w2,
                    float* __restrict__ attg,
                    float* __restrict__ avgs, float* __restrict__ maxs,
                    int* __restrict__ cnt){
  int b = blockIdx.x >> 6, r = blockIdx.x & 63, t = threadIdx.x;
  if (blockIdx.x == 0 && t == 0) cnt[0] = 0;    // reset kD3 barrier (stream order)
  __shared__ float sa[C_], sm[C_], pa[C_], pm[C_], hs[CR_], satt[C_];
  __shared__ float4 rs[16][16], rm[16][16];

  // EARLY: issue the 16 x-tile loads; latency hides behind the MLP below.
  int cg = t >> 4, q = t & 15;
  const float4* xb = (const float4*)x + (size_t)(b*C_ + cg*16)*(HW_/4) + (r<<4) + q;
  float4 xv[16];
  #pragma unroll
  for (int j = 0; j < 16; j++) xv[j] = xb[(size_t)j*(HW_/4)];

  sa[t] = avg[b*C_+t]; sm[t] = mxv[b*C_+t];
  __syncthreads();
  int h = t >> 4, seg = t & 15;                 // 16 hidden x 16 channel-segments
  float qa = 0.f, qm = 0.f;
  #pragma unroll
  for (int c2 = 0; c2 < 16; c2++){
    int c = seg*16 + c2;
    float ww = w1[h*C_ + c];
    qa += ww*sa[c]; qm += ww*sm[c];
  }
  pa[t] = qa; pm[t] = qm;
  __syncthreads();
  if (t < CR_){
    float ha = 0.f, hm = 0.f;
    #pragma unroll
    for (int s2 = 0; s2 < 16; s2++){ ha += pa[t*16+s2]; hm += pm[t*16+s2]; }
    hs[t] = fmaxf(ha, 0.f) + fmaxf(hm, 0.f);    // relu(h_avg)+relu(h_max), shared w2
  }
  __syncthreads();
  float o = 0.f;
  #pragma unroll
  for (int h2 = 0; h2 < CR_; h2++) o += hs[h2]*w2[t*CR_+h2];   // w2 is [C, CR]
  float attv = sigmoidf_(o);
  satt[t] = attv;
  if (r == 0) attg[b*C_+t] = attv;              // one writer per (b,c)
  __syncthreads();

  // per-row channel mean/max of x*att (x already in registers)
  float4 s = {0.f,0.f,0.f,0.f};
  float4 m = {-INFINITY,-INFINITY,-INFINITY,-INFINITY};
  #pragma unroll
  for (int j = 0; j < 16; j++){
    float a = satt[cg*16 + j];
    float vx=xv[j].x*a, vy=xv[j].y*a, vz=xv[j].z*a, vw=xv[j].w*a;
    s.x+=vx; s.y+=vy; s.z+=vz; s.w+=vw;
    m.x=fmaxf(m.x,vx); m.y=fmaxf(m.y,vy); m.z=fmaxf(m.z,vz); m.w=fmaxf(m.w,vw);
  }
  rs[cg][q] = s; rm[cg][q] = m;
  __syncthreads();
  if (t < 16){
    float4 Sv = {0.f,0.f,0.f,0.f};
    float4 Mv = {-INFINITY,-INFINITY,-INFINITY,-INFINITY};
    #pragma unroll
    for (int g2 = 0; g2 < 16; g2++){
      float4 a = rs[g2][t], b2 = rm[g2][t];
      Sv.x+=a.x; Sv.y+=a.y; Sv.z+=a.z; Sv.w+=a.w;
      Mv.x=fmaxf(Mv.x,b2.x); Mv.y=fmaxf(Mv.y,b2.y); Mv.z=fmaxf(Mv.z,b2.z); Mv.w=fmaxf(Mv.w,b2.w);
    }
    Sv.x*=(1.f/C_); Sv.y*=(1.f/C_); Sv.z*=(1.f/C_); Sv.w*=(1.f/C_);
    ((float4*)(avgs + b*HW_ + r*64))[t] = Sv;
    ((float4*)(maxs + b*HW_ + r*64))[t] = Mv;
  }
}

// ---- D3: halo stage + 7x7 conv + sigmoid + out = x*att*sig, THEN (gated)
//      non-local attention with in-kernel device barrier. grid = 512 blocks
//      (2/CU co-resident), 32 channels/block. ----
__global__ void __launch_bounds__(256, 2) kD3(
    const float* __restrict__ x, const float* __restrict__ attg,
    const float* __restrict__ avgs, const float* __restrict__ maxs,
    const float* __restrict__ wsp, const float* __restrict__ gm,
    const float* __restrict__ wq, const float* __restrict__ bq,
    const float* __restrict__ wk, const float* __restrict__ bk,
    const float* __restrict__ wv, const float* __restrict__ bv,
    float* __restrict__ qb, float* __restrict__ kb, float* __restrict__ vb,
    float* __restrict__ out, int* __restrict__ cnt){
  int bx = blockIdx.x;
  int b = bx >> 7, rem = bx & 127, rt = rem >> 3, cp = rem & 7;
  int t = threadIdx.x;
  __shared__ union {
    struct {
      float savg[10][64], smax[10][64], ssig[4][64], satt[32], swsp[98];
    } p;                                              // conv phase (~6.8 KB)
    float sx[C_*32];                                  // qkv phase (32 KB)
    struct { float sq[CQ_], red[8], sl[HW_]; } f;     // softmax phase (~16.5 KB)
  } S;

  // EARLY: issue the 8 x-tile loads; latency hides behind staging + conv.
  int f4id = t & 63;
  int imgo = rt*64 + f4id;                      // float4 index within image
  const float4* x4 = (const float4*)x;
  float4 xv[8];
  {
    size_t g0 = (size_t)(b*C_ + cp*32 + (t>>6))*(HW_/4) + imgo;
    #pragma unroll
    for (int jj = 0; jj < 8; jj++) xv[jj] = x4[g0 + (size_t)jj*4*(HW_/4)];
  }

  if (t < 98) S.p.swsp[t] = wsp[t];
  if (t < 32) S.p.satt[t] = attg[b*C_ + cp*32 + t];
  for (int idx = t; idx < 640; idx += 256){
    int row = idx >> 6, col = idx & 63;
    int gr = rt*4 - 3 + row;                    // global image row (zero-padded)
    float s = 0.f, m = 0.f;
    if ((unsigned)gr < 64u){
      s = avgs[b*HW_ + gr*64 + col];
      m = maxs[b*HW_ + gr*64 + col];
    }
    S.p.savg[row][col] = s; S.p.smax[row][col] = m;
  }
  __syncthreads();
  int trow = t >> 6, col = t & 63;
  float acc = 0.f;
  #pragma unroll
  for (int ky = 0; ky < 7; ky++){
    #pragma unroll
    for (int kx = 0; kx < 7; kx++){
      int gx = col - 3 + kx;
      if ((unsigned)gx < 64u)
        acc += S.p.savg[trow+ky][gx]*S.p.swsp[ky*7+kx]
             + S.p.smax[trow+ky][gx]*S.p.swsp[49+ky*7+kx];
    }
  }
  S.p.ssig[trow][col] = sigmoidf_(acc);
  __syncthreads();
  float4 sg4 = ((const float4*)S.p.ssig)[f4id];
  float4* o4 = (float4*)out;
  #pragma unroll
  for (int jj = 0; jj < 8; jj++){
    int lc = (t>>6) + jj*4;                     // local channel (wave-uniform)
    float a = S.p.satt[lc];
    size_t g = (size_t)(b*C_ + cp*32 + lc)*(HW_/4) + imgo;
    float4 rr;
    rr.x = xv[jj].x*a*sg4.x; rr.y = xv[jj].y*a*sg4.y;
    rr.z = xv[jj].z*a*sg4.z; rr.w = xv[jj].w*a*sg4.w;
    o4[g] = rr;
  }

  // ---- Gated non-local attention (uniform branch; gamma==0 -> done) ----
  float g = gm[0];
  if (g == 0.f) return;

  // device barrier: out fully written before qkv reads (gamma!=0 path only)
  __syncthreads();
  if (t == 0){
    __threadfence();
    __hip_atomic_fetch_add(cnt, 1, __ATOMIC_RELEASE, __HIP_MEMORY_SCOPE_AGENT);
    while (__hip_atomic_load(cnt, __ATOMIC_ACQUIRE, __HIP_MEMORY_SCOPE_AGENT) < NDB)
      __builtin_amdgcn_s_sleep(1);
    __threadfence();
  }
  __syncthreads();

  // qkv: one 32-px tile per block (512 tiles total)
  {
    int b2 = bx >> 7, tile = bx & 127, p0 = tile*32;
    for (int idx = t; idx < C_*32; idx += 256){
      int c = idx >> 5, px = idx & 31;
      S.sx[idx] = out[(size_t)(b2*C_+c)*HW_ + p0 + px];
    }
    __syncthreads();
    for (int oi = t; oi < CQ_*32; oi += 256){
      int o = oi >> 5, px = oi & 31;
      float aq = bq[o], ak = bk[o];
      for (int c = 0; c < C_; c++){ float xvv = S.sx[c*32+px]; aq += xvv*wq[o*C_+c]; ak += xvv*wk[o*C_+c]; }
      qb[(size_t)(b2*CQ_+o)*HW_ + p0 + px] = aq;
      kb[(size_t)(b2*CQ_+o)*HW_ + p0 + px] = ak;
    }
    for (int oi = t; oi < C_*32; oi += 256){
      int o = oi >> 5, px = oi & 31;
      float av = bv[o];
      for (int c = 0; c < C_; c++) av += S.sx[c*32+px]*wv[o*C_+c];
      vb[(size_t)(b2*C_+o)*HW_ + p0 + px] = av;
    }
    __syncthreads();
  }

  // second barrier: qkv complete before softmax consumes k/v of other tiles
  if (t == 0){
    __threadfence();
    __hip_atomic_fetch_add(cnt, 1, __ATOMIC_RELEASE, __HIP_MEMORY_SCOPE_AGENT);
    while (__hip_atomic_load(cnt, __ATOMIC_ACQUIRE, __HIP_MEMORY_SCOPE_AGENT) < 2*NDB)
      __builtin_amdgcn_s_sleep(1);
    __threadfence();
  }
  __syncthreads();

  for (int gi = bx; gi < B_*HW_; gi += NDB){
    int b2 = gi >> 12, i = gi & (HW_-1);
    if (t < CQ_) S.f.sq[t] = qb[(size_t)(b2*CQ_+t)*HW_ + i];
    __syncthreads();
    float lmax = -INFINITY;
    for (int j = t; j < HW_; j += 256){
      float l = 0.f;
      for (int d = 0; d < CQ_; d++) l += S.f.sq[d]*kb[(size_t)(b2*CQ_+d)*HW_ + j];
      S.f.sl[j] = l; lmax = fmaxf(lmax, l);
    }
    for (int off = 32; off; off >>= 1) lmax = fmaxf(lmax, __shfl_down(lmax, off));
    if (!(t & 63)) S.f.red[t>>6] = lmax;
    __syncthreads();
    float M = fmaxf(fmaxf(S.f.red[0],S.f.red[1]), fmaxf(S.f.red[2],S.f.red[3]));
    float lsum = 0.f;
    for (int j = t; j < HW_; j += 256){ float p = expf(S.f.sl[j]-M); S.f.sl[j] = p; lsum += p; }
    for (int off = 32; off; off >>= 1) lsum += __shfl_down(lsum, off);
    if (!(t & 63)) S.f.red[4+(t>>6)] = lsum;
    __syncthreads();
    float inv = g/(S.f.red[4]+S.f.red[5]+S.f.red[6]+S.f.red[7]);
    float acc2 = 0.f;
    const float* vrow = vb + (size_t)(b2*C_+t)*HW_;
    for (int j = 0; j < HW_; j++) acc2 += S.f.sl[j]*vrow[j];
    out[(size_t)(b2*C_+t)*HW_ + i] += acc2*inv;
    __syncthreads();
  }
}

extern "C" void kernel_launch(void* const* d_in, const int* in_sizes, int n_in,
                              void* d_out, int out_size, void* d_ws, size_t ws_size,
                              hipStream_t stream){
  const float* x   = (const float*)d_in[0];
  const float* w1  = (const float*)d_in[1];
  const float* w2  = (const float*)d_in[2];
  const float* wsp = (const float*)d_in[3];
  const float* wq  = (const float*)d_in[4];
  const float* bq  = (const float*)d_in[5];
  const float* wk  = (const float*)d_in[6];
  const float* bk  = (const float*)d_in[7];
  const float* wv  = (const float*)d_in[8];
  const float* bv  = (const float*)d_in[9];
  const float* gm  = (const float*)d_in[10];
  float* out = (float*)d_out;
  float* ws  = (float*)d_ws;

  int*   cnt  = (int*)ws;                 // 64 B barrier region
  float* avg  = ws + 16;                  // 1024
  float* mxv  = avg  + B_*C_;             // 1024
  float* attg = mxv  + B_*C_;             // 1024
  float* avgs = attg + B_*C_;             // B*HW = 16384
  float* maxs = avgs + B_*HW_;            // 16384
  float* qb   = maxs + B_*HW_;            // B*CQ*HW = 524288 (gated)
  float* kb   = qb   + B_*CQ_*HW_;        // 524288 (gated)
  float* vb   = kb   + B_*CQ_*HW_;        // B*C*HW = 4194304 (gated)
  (void)in_sizes; (void)n_in; (void)out_size; (void)ws_size;

  kA <<<B_*C_, 256, 0, stream>>>(x, avg, mxv);
  kBC<<<256,   256, 0, stream>>>(x, avg, mxv, w1, w2, attg, avgs, maxs, cnt);
  kD3<<<NDB,   256, 0, stream>>>(x, attg, avgs, maxs, wsp, gm,
                                 wq, bq, wk, bk, wv, bv, qb, kb, vb, out, cnt);
}